// Round 11
// baseline (171.465 us; speedup 1.0000x reference)
//
#include <hip/hip_runtime.h>
#include <hip/hip_bf16.h>
#include <math.h>

// Problem constants (fixed by reference setup_inputs)
constexpr int NROWS = 8192;   // B
constexpr int HDIM  = 256;    // H (= K of the GEMM)
constexpr int N2    = 16384;  // 2*B rows of Z
constexpr int BM    = 128;    // tile M = tile N
constexpr int NTILE = N2 / BM;        // 128 tile-rows
constexpr int NBLK  = NTILE * (NTILE + 1) / 2;  // 8256 upper-tri tiles

// sqrt(2 * log2(e)): Z pre-scaled so Zs_i.Zs_j = 2*log2(e)*cos and
// exp2(acc) == exp(sim/tau), tau = 0.5
constexpr float PRESCALE = 1.69864357f;

typedef __attribute__((ext_vector_type(4))) float floatx4;
typedef __attribute__((ext_vector_type(8))) short shortx8; // 8 bf16 = 4 VGPRs

// DPP row_shl add: VALU pipe, not DS (R9: -18us vs ds_bpermute shuffles).
#define DPP_ROW_SHL_ADD(v, CTRL) do {                                        \
    union { float f; int i; } _u, _r; _u.f = (v);                            \
    _r.i = __builtin_amdgcn_update_dpp(0, _u.i, (CTRL), 0xF, 0xF, true);     \
    (v) += _r.f; } while (0)

// Packed-Z layout ("fragment order"): 16-row tiles, 8-elem k-chunks:
//   Zp[tile = row/16][chunk c = k/8][m = row%16]  -> 16B units
//   elem addr = tile*4096 + c*128 + m*8   (tile stride 8KB)
// A wave's MFMA fragment (16 rows x k-step) is then Zp + tile*4096 +
// s*512 + lane*8  — ONE contiguous 1KB segment per global_load_dwordx4.
// This fixes R7's failure (row-major frag loads = 16 scattered segments
// per inst saturated TA) and removes the entire LDS round-trip of R6-R10
// (2.06 GB ds_read + 1.03 GB LDS write + per-chunk barriers).

// ---------------------------------------------------------------------------
// Kernel 1: wave-per-row L2-normalize -> bf16 Zp (pre-scaled, PACKED layout);
// pos = cos(x,y). Also zeroes rowsum and out.
// Lane l holds k = 4l..4l+3 -> chunk c = l>>1, half = l&1 (8B store).
// ---------------------------------------------------------------------------
__global__ __launch_bounds__(256) void normalize_kernel(
    const float* __restrict__ x, const float* __restrict__ y,
    __hip_bfloat16* __restrict__ Zp, float* __restrict__ pos,
    float* __restrict__ rowsum, float* __restrict__ out)
{
    const int wave = threadIdx.x >> 6, lane = threadIdx.x & 63;
    const int row  = blockIdx.x * 4 + wave;           // grid 2048 -> 8192 rows

    const float4 xv = ((const float4*)x)[row * 64 + lane];
    const float4 yv = ((const float4*)y)[row * 64 + lane];

    float sx  = xv.x*xv.x + xv.y*xv.y + xv.z*xv.z + xv.w*xv.w;
    float sy  = yv.x*yv.x + yv.y*yv.y + yv.z*yv.z + yv.w*yv.w;
    float sxy = xv.x*yv.x + xv.y*yv.y + xv.z*yv.z + xv.w*yv.w;
    #pragma unroll
    for (int m = 1; m < 64; m <<= 1) {
        sx  += __shfl_xor(sx,  m);
        sy  += __shfl_xor(sy,  m);
        sxy += __shfl_xor(sxy, m);
    }
    const float rxn = rsqrtf(sx), ryn = rsqrtf(sy);
    const float rx = rxn * PRESCALE, ry = ryn * PRESCALE;

    union { ushort4 u; __hip_bfloat16 h[4]; } zx, zy;
    zx.h[0] = __float2bfloat16(xv.x * rx); zx.h[1] = __float2bfloat16(xv.y * rx);
    zx.h[2] = __float2bfloat16(xv.z * rx); zx.h[3] = __float2bfloat16(xv.w * rx);
    zy.h[0] = __float2bfloat16(yv.x * ry); zy.h[1] = __float2bfloat16(yv.y * ry);
    zy.h[2] = __float2bfloat16(yv.z * ry); zy.h[3] = __float2bfloat16(yv.w * ry);

    // packed store: tile = row>>4, m = row&15, chunk = lane>>1, half = lane&1
    const int tile = row >> 4, m = row & 15;
    const size_t off = (size_t)tile * 4096 + (lane >> 1) * 128 + m * 8 + (lane & 1) * 4;
    *(ushort4*)(Zp + off)                 = zx.u;   // x -> tiles 0..511
    *(ushort4*)(Zp + off + 512 * 4096)    = zy.u;   // y -> tiles 512..1023

    if (lane == 0) {
        const float p = sxy * rxn * ryn;
        pos[row]         = p;
        pos[row + NROWS] = p;
    }
    const int gt = blockIdx.x * 256 + threadIdx.x;
    if (gt < N2) rowsum[gt] = 0.f;
    if (gt == 0) out[0] = 0.f;
}

// ---------------------------------------------------------------------------
// Kernel 2: upper-triangle tiled Zp·Zp^T, fused exp2 + row/col sums.
// LDS-FREE: fragments loaded straight from packed Zp (1KB coalesced per
// inst), register double-buffered one k-step ahead. NO barriers in the
// K-loop — waves drift independently; L1/L2 serve the reuse that LDS used
// to (R10 post-mortem: LDS round-trip serialized DS/VALU/MFMA pipes at
// ~250k cyc/CU vs 97k max-pipe floor). XCD-locality mapping kept (R8:
// FETCH 159->31 MB). NO device-scope fences (R5). Epilogue: DPP row-sums
// (R9), shfl col-sums, LDS accumulate, global atomics.
// ---------------------------------------------------------------------------
__global__ __launch_bounds__(256, 3) void simgemm_kernel(
    const __hip_bfloat16* __restrict__ Zp, float* __restrict__ rowsum)
{
    // ---- XCD-local block -> (bi,bj) mapping (bijection onto upper tri) ----
    const int b = blockIdx.x;
    const int k = b & 7;        // XCD under round-robin dispatch heuristic
    const int m = b >> 3;       // 0..1031 local rank within XCD
    int bi, bj;
    if (m < 136) {
        // diagonal group-pair k: 16x16 upper triangle, cum(t) = t*(33-t)/2
        int ti = (int)((33.0f - sqrtf(1089.0f - 8.0f * (float)m)) * 0.5f);
        if (m < ti * (33 - ti) / 2) ti--;
        else if (m >= (ti + 1) * (32 - ti) / 2) ti++;
        const int tj = ti + (m - ti * (33 - ti) / 2);
        bi = k * 16 + ti;
        bj = k * 16 + tj;
    } else {
        const int m2 = m - 136;          // 0..895
        const int hh = m2 >> 7;          // 0..6  (which of my 7 halves)
        const int r  = m2 & 127;         // 0..127 within half (8x16 tiles)
        const int h  = hh * 8 + k;       // 0..55 global half index
        const int q  = h >> 1;           // 0..27 off-diag group pair
        const int sub = h & 1;
        // pair q -> (gi,gj), gi<gj, cum(gi) = gi*(15-gi)/2
        int gi = 0;
        #pragma unroll
        for (int t = 6; t > 0; --t)
            if (q >= t * (15 - t) / 2) { gi = t; break; }
        const int gj = gi + 1 + (q - gi * (15 - gi) / 2);
        bi = gi * 16 + sub * 8 + (r >> 4);
        bj = gj * 16 + (r & 15);
    }
    const bool diag = (bi == bj);

    __shared__ float rs[BM];
    __shared__ float cs[BM];

    const int tid  = threadIdx.x;
    const int wave = tid >> 6;
    const int lane = tid & 63;
    const int wm   = wave & 1;            // wave row (0..1)
    const int wn   = wave >> 1;           // wave col (0..1)
    const int g    = lane >> 4;           // quad  (0..3)
    const int m15  = lane & 15;

    if (tid < BM) { rs[tid] = 0.f; cs[tid] = 0.f; }
    __syncthreads();   // rs/cs zeroed before any wave's epilogue atomics

    // fragment base pointers (packed layout): frag (f, s) at
    //   base + f*4096 + s*512  elements, lane offset lane*8.
    const __hip_bfloat16* pA = Zp + (size_t)(bi * 8 + wm * 4) * 4096 + lane * 8;
    const __hip_bfloat16* pB = Zp + (size_t)(bj * 8 + wn * 4) * 4096 + lane * 8;

    floatx4 acc[4][4] = {};
    shortx8 af[2][4], bf[2][4];

    #pragma unroll
    for (int f = 0; f < 4; ++f) {
        af[0][f] = *(const shortx8*)(pA + f * 4096);
        bf[0][f] = *(const shortx8*)(pB + f * 4096);
    }

    #pragma unroll
    for (int s = 0; s < HDIM / 32; ++s) {   // 8 k-steps, no barriers
        const int cur = s & 1;
        if (s + 1 < HDIM / 32) {
            #pragma unroll
            for (int f = 0; f < 4; ++f) {
                af[cur ^ 1][f] = *(const shortx8*)(pA + f * 4096 + (s + 1) * 512);
                bf[cur ^ 1][f] = *(const shortx8*)(pB + f * 4096 + (s + 1) * 512);
            }
        }
        #pragma unroll
        for (int fm = 0; fm < 4; ++fm)
            #pragma unroll
            for (int fn = 0; fn < 4; ++fn)
                acc[fm][fn] = __builtin_amdgcn_mfma_f32_16x16x32_bf16(
                    af[cur][fm], bf[cur][fn], acc[fm][fn], 0, 0, 0);
    }

    // ---- epilogue: e = exp2(acc) (== exp(sim/tau)), reduce rows & cols ----
    float rp[4][4] = {{0.f}};  // [fm][reg] partial row sums
    float cp[4]    = {0.f};    // [fn]      partial col sums

    if (!diag) {
        #pragma unroll
        for (int fm = 0; fm < 4; ++fm)
            #pragma unroll
            for (int fn = 0; fn < 4; ++fn) {
                const floatx4 a = acc[fm][fn];
                #pragma unroll
                for (int q = 0; q < 4; ++q) {
                    const float e = __builtin_amdgcn_exp2f(a[q]);
                    rp[fm][q] += e;
                    cp[fn]    += e;
                }
            }
    } else {
        #pragma unroll
        for (int fm = 0; fm < 4; ++fm)
            #pragma unroll
            for (int fn = 0; fn < 4; ++fn) {
                const floatx4 a = acc[fm][fn];
                const int cl = wn * 64 + fn * 16 + m15;
                #pragma unroll
                for (int q = 0; q < 4; ++q) {
                    const int rl = wm * 64 + fm * 16 + g * 4 + q;
                    float e = __builtin_amdgcn_exp2f(a[q]);
                    if (cl <= rl) e = 0.f;   // strictly-upper only
                    rp[fm][q] += e;
                    cp[fn]    += e;
                }
            }
    }

    // row sums: 16-lane DPP reduction (VALU pipe); total lands in m15==0
    #pragma unroll
    for (int fm = 0; fm < 4; ++fm)
        #pragma unroll
        for (int q = 0; q < 4; ++q) {
            float v = rp[fm][q];
            DPP_ROW_SHL_ADD(v, 0x101);   // row_shl:1
            DPP_ROW_SHL_ADD(v, 0x102);   // row_shl:2
            DPP_ROW_SHL_ADD(v, 0x104);   // row_shl:4
            DPP_ROW_SHL_ADD(v, 0x108);   // row_shl:8
            rp[fm][q] = v;
        }
    if (m15 == 0) {
        #pragma unroll
        for (int fm = 0; fm < 4; ++fm)
            #pragma unroll
            for (int q = 0; q < 4; ++q)
                atomicAdd(&rs[wm * 64 + fm * 16 + g * 4 + q], rp[fm][q]);
    }

    // col sums: reduce across quads (xor 16/32 crosses DPP rows -> keep shfl)
    #pragma unroll
    for (int mask = 16; mask < 64; mask <<= 1)
        #pragma unroll
        for (int fn = 0; fn < 4; ++fn)
            cp[fn] += __shfl_xor(cp[fn], mask);
    if (g == 0) {
        #pragma unroll
        for (int fn = 0; fn < 4; ++fn)
            atomicAdd(&cs[wn * 64 + fn * 16 + m15], cp[fn]);
    }

    __syncthreads();
    if (tid < BM) {
        atomicAdd(&rowsum[(size_t)bi * BM + tid], rs[tid]);
        atomicAdd(&rowsum[(size_t)bj * BM + tid], cs[tid]);
    }
}

// ---------------------------------------------------------------------------
// Kernel 3: loss = mean( log(rowsum_i) - 2*pos_i ), 16 blocks + atomic.
// out[0] zeroed by normalize_kernel (stream-ordered).
// ---------------------------------------------------------------------------
__global__ __launch_bounds__(1024) void finalize_kernel(
    const float* __restrict__ rowsum, const float* __restrict__ pos,
    float* __restrict__ out)
{
    const int i = threadIdx.x + blockIdx.x * 1024;
    float s = logf(rowsum[i]) - 2.0f * pos[i];
    #pragma unroll
    for (int off = 32; off; off >>= 1) s += __shfl_down(s, off);
    __shared__ float sh[16];
    const int lt = threadIdx.x;
    if ((lt & 63) == 0) sh[lt >> 6] = s;
    __syncthreads();
    if (lt == 0) {
        float tot = 0.f;
        #pragma unroll
        for (int w = 0; w < 16; ++w) tot += sh[w];
        atomicAdd(out, tot / (float)N2);
    }
}

// ---------------------------------------------------------------------------
extern "C" void kernel_launch(void* const* d_in, const int* in_sizes, int n_in,
                              void* d_out, int out_size, void* d_ws, size_t ws_size,
                              hipStream_t stream)
{
    const float* x = (const float*)d_in[0];
    const float* y = (const float*)d_in[1];

    // workspace: Zp bf16 packed [16384*256] (8 MB) | rowsum f32 | pos f32
    __hip_bfloat16* Zp = (__hip_bfloat16*)d_ws;
    float* rowsum = (float*)((char*)d_ws + (size_t)N2 * HDIM * sizeof(__hip_bfloat16));
    float* pos    = rowsum + N2;

    normalize_kernel<<<NROWS / 4, 256, 0, stream>>>(x, y, Zp, pos, rowsum, (float*)d_out);
    simgemm_kernel<<<NBLK, 256, 0, stream>>>(Zp, rowsum);
    finalize_kernel<<<N2 / 1024, 1024, 0, stream>>>(rowsum, pos, (float*)d_out);
}

// Round 12
// 165.739 us; speedup vs baseline: 1.0346x; 1.0346x over previous
//
#include <hip/hip_runtime.h>
#include <hip/hip_bf16.h>
#include <math.h>

// Problem constants (fixed by reference setup_inputs)
constexpr int NROWS = 8192;   // B
constexpr int HDIM  = 256;    // H (= K of the GEMM)
constexpr int N2    = 16384;  // 2*B rows of Z
constexpr int BM    = 128;    // tile M = tile N
constexpr int NTILE = N2 / BM;        // 128 tile-rows
constexpr int NBLK  = NTILE * (NTILE + 1) / 2;  // 8256 upper-tri tiles

// sqrt(2 * log2(e)): Z pre-scaled so Zs_i.Zs_j = 2*log2(e)*cos and
// exp2(acc) == exp(sim/tau), tau = 0.5
constexpr float PRESCALE = 1.69864357f;

typedef __attribute__((ext_vector_type(4))) float floatx4;
typedef __attribute__((ext_vector_type(8))) short shortx8; // 8 bf16 = 4 VGPRs

// DPP helpers (VALU pipe, not DS — R9: -18us vs ds_bpermute shuffles).
#define DPP_ADD(v, CTRL) do {                                                \
    union { float f; int i; } _u, _r; _u.f = (v);                            \
    _r.i = __builtin_amdgcn_update_dpp(0, _u.i, (CTRL), 0xF, 0xF, true);     \
    (v) += _r.f; } while (0)
// 16-lane row sum into lane0 of each row: row_shl 1,2,4,8
#define DPP_ROW_SUM16(v) do { DPP_ADD(v,0x101); DPP_ADD(v,0x102);            \
    DPP_ADD(v,0x104); DPP_ADD(v,0x108); } while (0)
// 16-lane sum, result in ALL 16 lanes: quad_perm xor1, xor2, row_ror 4, 8
#define DPP_ALL_SUM16(v) do { DPP_ADD(v,0xB1); DPP_ADD(v,0x4E);              \
    DPP_ADD(v,0x124); DPP_ADD(v,0x128); } while (0)

// Packed-Z layout ("fragment order"): 16-row tiles, 8-elem k-chunks:
//   Zp[tile = row/16][chunk c = k/8][m = row%16]  -> 16B units
//   elem addr = tile*4096 + c*128 + m*8   (tile stride 8KB)
// A wave's MFMA fragment (16 rows x one k-step) is Zp + tile*4096 + s*512
// + lane*8 — ONE contiguous 1KB segment per global_load_dwordx4 (fixes R7's
// 16-scattered-segment TA saturation; removes R6-R10's LDS round-trip).

// ---------------------------------------------------------------------------
// Kernel 1: wave-per-row L2-normalize -> bf16 Zp (pre-scaled, PACKED layout);
// pos = cos(x,y). Reductions via DPP (6 cross-lane ops vs 18 bpermutes).
// Also zeroes rowsum and out.
// ---------------------------------------------------------------------------
__global__ __launch_bounds__(256) void normalize_kernel(
    const float* __restrict__ x, const float* __restrict__ y,
    __hip_bfloat16* __restrict__ Zp, float* __restrict__ pos,
    float* __restrict__ rowsum, float* __restrict__ out)
{
    const int wave = threadIdx.x >> 6, lane = threadIdx.x & 63;
    const int row  = blockIdx.x * 4 + wave;           // grid 2048 -> 8192 rows

    const float4 xv = ((const float4*)x)[row * 64 + lane];
    const float4 yv = ((const float4*)y)[row * 64 + lane];

    float sx  = xv.x*xv.x + xv.y*xv.y + xv.z*xv.z + xv.w*xv.w;
    float sy  = yv.x*yv.x + yv.y*yv.y + yv.z*yv.z + yv.w*yv.w;
    float sxy = xv.x*yv.x + xv.y*yv.y + xv.z*yv.z + xv.w*yv.w;
    // 16-lane DPP all-sum, then 2 shfl_xor to cross 16/32 boundaries
    DPP_ALL_SUM16(sx); DPP_ALL_SUM16(sy); DPP_ALL_SUM16(sxy);
    sx  += __shfl_xor(sx, 16);  sx  += __shfl_xor(sx, 32);
    sy  += __shfl_xor(sy, 16);  sy  += __shfl_xor(sy, 32);
    sxy += __shfl_xor(sxy, 16); sxy += __shfl_xor(sxy, 32);

    const float rxn = rsqrtf(sx), ryn = rsqrtf(sy);
    const float rx = rxn * PRESCALE, ry = ryn * PRESCALE;

    union { ushort4 u; __hip_bfloat16 h[4]; } zx, zy;
    zx.h[0] = __float2bfloat16(xv.x * rx); zx.h[1] = __float2bfloat16(xv.y * rx);
    zx.h[2] = __float2bfloat16(xv.z * rx); zx.h[3] = __float2bfloat16(xv.w * rx);
    zy.h[0] = __float2bfloat16(yv.x * ry); zy.h[1] = __float2bfloat16(yv.y * ry);
    zy.h[2] = __float2bfloat16(yv.z * ry); zy.h[3] = __float2bfloat16(yv.w * ry);

    // packed store: tile = row>>4, m = row&15, chunk = lane>>1, half = lane&1
    const int tile = row >> 4, m = row & 15;
    const size_t off = (size_t)tile * 4096 + (lane >> 1) * 128 + m * 8 + (lane & 1) * 4;
    *(ushort4*)(Zp + off)                 = zx.u;   // x -> tiles 0..511
    *(ushort4*)(Zp + off + 512 * 4096)    = zy.u;   // y -> tiles 512..1023

    if (lane == 0) {
        const float p = sxy * rxn * ryn;
        pos[row]         = p;
        pos[row + NROWS] = p;
    }
    const int gt = blockIdx.x * 256 + threadIdx.x;
    if (gt < N2) rowsum[gt] = 0.f;
    if (gt == 0) out[0] = 0.f;
}

// ---------------------------------------------------------------------------
// Kernel 2: upper-triangle tiled Zp·Zp^T, fused exp2 + row/col sums.
// LDS-free packed-fragment GEMM (R11) with DEPTH-2 register pipeline:
// 3 fragment buffers; body s loads k-step s+2 while MFMAing step s ->
// ~2x the load-latency slack of R11's depth-1 (whose exposed ~100-200cyc
// stall per step capped MfmaUtil at 25%). No K-loop barriers; waves drift.
// XCD-locality mapping kept (R8: FETCH 159->31MB). NO device-scope fences
// (R5). Epilogue: DPP row-sums (R9), shfl col-sums, LDS acc, global atomics.
// ---------------------------------------------------------------------------
__global__ __launch_bounds__(256, 3) void simgemm_kernel(
    const __hip_bfloat16* __restrict__ Zp, float* __restrict__ rowsum)
{
    // ---- XCD-local block -> (bi,bj) mapping (bijection onto upper tri) ----
    const int b = blockIdx.x;
    const int k = b & 7;        // XCD under round-robin dispatch heuristic
    const int m = b >> 3;       // 0..1031 local rank within XCD
    int bi, bj;
    if (m < 136) {
        // diagonal group-pair k: 16x16 upper triangle, cum(t) = t*(33-t)/2
        int ti = (int)((33.0f - sqrtf(1089.0f - 8.0f * (float)m)) * 0.5f);
        if (m < ti * (33 - ti) / 2) ti--;
        else if (m >= (ti + 1) * (32 - ti) / 2) ti++;
        const int tj = ti + (m - ti * (33 - ti) / 2);
        bi = k * 16 + ti;
        bj = k * 16 + tj;
    } else {
        const int m2 = m - 136;          // 0..895
        const int hh = m2 >> 7;          // 0..6  (which of my 7 halves)
        const int r  = m2 & 127;         // 0..127 within half (8x16 tiles)
        const int h  = hh * 8 + k;       // 0..55 global half index
        const int q  = h >> 1;           // 0..27 off-diag group pair
        const int sub = h & 1;
        // pair q -> (gi,gj), gi<gj, cum(gi) = gi*(15-gi)/2
        int gi = 0;
        #pragma unroll
        for (int t = 6; t > 0; --t)
            if (q >= t * (15 - t) / 2) { gi = t; break; }
        const int gj = gi + 1 + (q - gi * (15 - gi) / 2);
        bi = gi * 16 + sub * 8 + (r >> 4);
        bj = gj * 16 + (r & 15);
    }
    const bool diag = (bi == bj);

    __shared__ float rs[BM];
    __shared__ float cs[BM];

    const int tid  = threadIdx.x;
    const int wave = tid >> 6;
    const int lane = tid & 63;
    const int wm   = wave & 1;            // wave row (0..1)
    const int wn   = wave >> 1;           // wave col (0..1)
    const int g    = lane >> 4;           // quad  (0..3)
    const int m15  = lane & 15;

    if (tid < BM) { rs[tid] = 0.f; cs[tid] = 0.f; }
    __syncthreads();   // rs/cs zeroed before any wave's epilogue atomics

    // fragment base pointers (packed layout): frag (f, s) at
    //   base + f*4096 + s*512  elements, lane offset lane*8.
    const __hip_bfloat16* pA = Zp + (size_t)(bi * 8 + wm * 4) * 4096 + lane * 8;
    const __hip_bfloat16* pB = Zp + (size_t)(bj * 8 + wn * 4) * 4096 + lane * 8;

    floatx4 acc[4][4] = {};
    shortx8 af[3][4], bf[3][4];   // depth-2: 3 buffers

    #pragma unroll
    for (int f = 0; f < 4; ++f) {
        af[0][f] = *(const shortx8*)(pA + f * 4096);
        bf[0][f] = *(const shortx8*)(pB + f * 4096);
    }
    #pragma unroll
    for (int f = 0; f < 4; ++f) {
        af[1][f] = *(const shortx8*)(pA + f * 4096 + 512);
        bf[1][f] = *(const shortx8*)(pB + f * 4096 + 512);
    }

    #pragma unroll
    for (int s = 0; s < HDIM / 32; ++s) {   // 8 k-steps, no barriers
        const int cur = s % 3;
        if (s + 2 < HDIM / 32) {
            const int nxt = (s + 2) % 3;
            #pragma unroll
            for (int f = 0; f < 4; ++f) {
                af[nxt][f] = *(const shortx8*)(pA + f * 4096 + (s + 2) * 512);
                bf[nxt][f] = *(const shortx8*)(pB + f * 4096 + (s + 2) * 512);
            }
        }
        #pragma unroll
        for (int fm = 0; fm < 4; ++fm)
            #pragma unroll
            for (int fn = 0; fn < 4; ++fn)
                acc[fm][fn] = __builtin_amdgcn_mfma_f32_16x16x32_bf16(
                    af[cur][fm], bf[cur][fn], acc[fm][fn], 0, 0, 0);
    }

    // ---- epilogue: e = exp2(acc) (== exp(sim/tau)), reduce rows & cols ----
    float rp[4][4] = {{0.f}};  // [fm][reg] partial row sums
    float cp[4]    = {0.f};    // [fn]      partial col sums

    if (!diag) {
        #pragma unroll
        for (int fm = 0; fm < 4; ++fm)
            #pragma unroll
            for (int fn = 0; fn < 4; ++fn) {
                const floatx4 a = acc[fm][fn];
                #pragma unroll
                for (int q = 0; q < 4; ++q) {
                    const float e = __builtin_amdgcn_exp2f(a[q]);
                    rp[fm][q] += e;
                    cp[fn]    += e;
                }
            }
    } else {
        #pragma unroll
        for (int fm = 0; fm < 4; ++fm)
            #pragma unroll
            for (int fn = 0; fn < 4; ++fn) {
                const floatx4 a = acc[fm][fn];
                const int cl = wn * 64 + fn * 16 + m15;
                #pragma unroll
                for (int q = 0; q < 4; ++q) {
                    const int rl = wm * 64 + fm * 16 + g * 4 + q;
                    float e = __builtin_amdgcn_exp2f(a[q]);
                    if (cl <= rl) e = 0.f;   // strictly-upper only
                    rp[fm][q] += e;
                    cp[fn]    += e;
                }
            }
    }

    // row sums: 16-lane DPP reduction (VALU pipe); total lands in m15==0
    #pragma unroll
    for (int fm = 0; fm < 4; ++fm)
        #pragma unroll
        for (int q = 0; q < 4; ++q) {
            float v = rp[fm][q];
            DPP_ROW_SUM16(v);
            rp[fm][q] = v;
        }
    if (m15 == 0) {
        #pragma unroll
        for (int fm = 0; fm < 4; ++fm)
            #pragma unroll
            for (int q = 0; q < 4; ++q)
                atomicAdd(&rs[wm * 64 + fm * 16 + g * 4 + q], rp[fm][q]);
    }

    // col sums: reduce across quads (xor 16/32 crosses DPP rows -> keep shfl)
    #pragma unroll
    for (int mask = 16; mask < 64; mask <<= 1)
        #pragma unroll
        for (int fn = 0; fn < 4; ++fn)
            cp[fn] += __shfl_xor(cp[fn], mask);
    if (g == 0) {
        #pragma unroll
        for (int fn = 0; fn < 4; ++fn)
            atomicAdd(&cs[wn * 64 + fn * 16 + m15], cp[fn]);
    }

    __syncthreads();
    if (tid < BM) {
        atomicAdd(&rowsum[(size_t)bi * BM + tid], rs[tid]);
        atomicAdd(&rowsum[(size_t)bj * BM + tid], cs[tid]);
    }
}

// ---------------------------------------------------------------------------
// Kernel 3: loss = mean( log(rowsum_i) - 2*pos_i ), 16 blocks + atomic.
// out[0] zeroed by normalize_kernel (stream-ordered).
// ---------------------------------------------------------------------------
__global__ __launch_bounds__(1024) void finalize_kernel(
    const float* __restrict__ rowsum, const float* __restrict__ pos,
    float* __restrict__ out)
{
    const int i = threadIdx.x + blockIdx.x * 1024;
    float s = logf(rowsum[i]) - 2.0f * pos[i];
    #pragma unroll
    for (int off = 32; off; off >>= 1) s += __shfl_down(s, off);
    __shared__ float sh[16];
    const int lt = threadIdx.x;
    if ((lt & 63) == 0) sh[lt >> 6] = s;
    __syncthreads();
    if (lt == 0) {
        float tot = 0.f;
        #pragma unroll
        for (int w = 0; w < 16; ++w) tot += sh[w];
        atomicAdd(out, tot / (float)N2);
    }
}

// ---------------------------------------------------------------------------
extern "C" void kernel_launch(void* const* d_in, const int* in_sizes, int n_in,
                              void* d_out, int out_size, void* d_ws, size_t ws_size,
                              hipStream_t stream)
{
    const float* x = (const float*)d_in[0];
    const float* y = (const float*)d_in[1];

    // workspace: Zp bf16 packed [16384*256] (8 MB) | rowsum f32 | pos f32
    __hip_bfloat16* Zp = (__hip_bfloat16*)d_ws;
    float* rowsum = (float*)((char*)d_ws + (size_t)N2 * HDIM * sizeof(__hip_bfloat16));
    float* pos    = rowsum + N2;

    normalize_kernel<<<NROWS / 4, 256, 0, stream>>>(x, y, Zp, pos, rowsum, (float*)d_out);
    simgemm_kernel<<<NBLK, 256, 0, stream>>>(Zp, rowsum);
    finalize_kernel<<<N2 / 1024, 1024, 0, stream>>>(rowsum, pos, (float*)d_out);
}

// Round 13
// 163.336 us; speedup vs baseline: 1.0498x; 1.0147x over previous
//
#include <hip/hip_runtime.h>
#include <hip/hip_bf16.h>
#include <hip/hip_fp8.h>
#include <math.h>

// Problem constants (fixed by reference setup_inputs)
constexpr int NROWS = 8192;   // B
constexpr int HDIM  = 256;    // H (= K of the GEMM)
constexpr int N2    = 16384;  // 2*B rows of Z
constexpr int BM    = 128;    // tile M = tile N
constexpr int NTILE = N2 / BM;        // 128 tile-rows
constexpr int NBLK  = NTILE * (NTILE + 1) / 2;  // 8256 upper-tri tiles

// Z stored as fp8 e4m3 of (z_hat * 16): elements ~N(0,1) -> good e4m3
// coverage (rms quant err ~3.6%). acc = 256*cos + eps; epilogue scales by
// 2*log2(e)/256 so exp2() gives exp(sim/tau), tau=0.5.
constexpr float ZSCALE    = 16.0f;
constexpr float ACC2EXP2  = 2.885390082f / 256.0f;   // 2*log2(e)/256

typedef __attribute__((ext_vector_type(4))) float floatx4;

// DPP helpers (VALU pipe, not DS — R9: -18us vs ds_bpermute shuffles).
#define DPP_ADD(v, CTRL) do {                                                \
    union { float f; int i; } _u, _r; _u.f = (v);                            \
    _r.i = __builtin_amdgcn_update_dpp(0, _u.i, (CTRL), 0xF, 0xF, true);     \
    (v) += _r.f; } while (0)
// 16-lane row sum into lane0 of each row: row_shl 1,2,4,8
#define DPP_ROW_SUM16(v) do { DPP_ADD(v,0x101); DPP_ADD(v,0x102);            \
    DPP_ADD(v,0x104); DPP_ADD(v,0x108); } while (0)
// 16-lane sum, result in ALL 16 lanes: quad_perm xor1, xor2, row_ror 4, 8
#define DPP_ALL_SUM16(v) do { DPP_ADD(v,0xB1); DPP_ADD(v,0x4E);              \
    DPP_ADD(v,0x124); DPP_ADD(v,0x128); } while (0)

// Packed-Zp8 layout (fragment order, BYTE addressed): 16-row tiles, 8-elem
// k-chunks: addr = tile*4096 + chunk*128 + m*8 + j   (tile = 16x256 B).
// A wave's 16x16x32 fp8 fragment (lane m=l&15, quad g=l>>4, k-step s) is
// one contiguous 512B segment: base + tile*4096 + s*512 + l*8, loaded as
// a single global_load_dwordx2 (8 cache lines/inst vs bf16's 16 -> halves
// the TA/L1 line traffic that R12's model put at ~132k cyc/CU = top pipe).

// ---------------------------------------------------------------------------
// Kernel 1: wave-per-row L2-normalize -> fp8 Zp8 (x16, PACKED layout);
// pos = cos(x,y) in fp32. DPP reductions. Also zeroes rowsum and out.
// ---------------------------------------------------------------------------
__global__ __launch_bounds__(256) void normalize_kernel(
    const float* __restrict__ x, const float* __restrict__ y,
    unsigned char* __restrict__ Zp8, float* __restrict__ pos,
    float* __restrict__ rowsum, float* __restrict__ out)
{
    const int wave = threadIdx.x >> 6, lane = threadIdx.x & 63;
    const int row  = blockIdx.x * 4 + wave;           // grid 2048 -> 8192 rows

    const float4 xv = ((const float4*)x)[row * 64 + lane];
    const float4 yv = ((const float4*)y)[row * 64 + lane];

    float sx  = xv.x*xv.x + xv.y*xv.y + xv.z*xv.z + xv.w*xv.w;
    float sy  = yv.x*yv.x + yv.y*yv.y + yv.z*yv.z + yv.w*yv.w;
    float sxy = xv.x*yv.x + xv.y*yv.y + xv.z*yv.z + xv.w*yv.w;
    DPP_ALL_SUM16(sx); DPP_ALL_SUM16(sy); DPP_ALL_SUM16(sxy);
    sx  += __shfl_xor(sx, 16);  sx  += __shfl_xor(sx, 32);
    sy  += __shfl_xor(sy, 16);  sy  += __shfl_xor(sy, 32);
    sxy += __shfl_xor(sxy, 16); sxy += __shfl_xor(sxy, 32);

    const float rxn = rsqrtf(sx), ryn = rsqrtf(sy);
    const float rx = rxn * ZSCALE, ry = ryn * ZSCALE;

    // pack 4 floats -> 4 fp8 e4m3 bytes (OCP)
    auto pack4 = [](float a, float b, float c, float d) -> unsigned int {
        __hip_fp8_e4m3 f0(a), f1(b), f2(c), f3(d);
        return (unsigned int)f0.__x | ((unsigned int)f1.__x << 8) |
               ((unsigned int)f2.__x << 16) | ((unsigned int)f3.__x << 24);
    };
    const unsigned int wx = pack4(xv.x * rx, xv.y * rx, xv.z * rx, xv.w * rx);
    const unsigned int wy = pack4(yv.x * ry, yv.y * ry, yv.z * ry, yv.w * ry);

    // packed store: tile = row>>4, m = row&15; lane l holds k=4l..4l+3 ->
    // chunk = l>>1, byte-in-chunk = (l&1)*4
    const int tile = row >> 4, m = row & 15;
    const size_t off = (size_t)tile * 4096 + (lane >> 1) * 128 + m * 8 + (lane & 1) * 4;
    *(unsigned int*)(Zp8 + off)                         = wx;  // x: tiles 0..511
    *(unsigned int*)(Zp8 + off + (size_t)512 * 4096)    = wy;  // y: tiles 512..1023

    if (lane == 0) {
        const float p = sxy * rxn * ryn;
        pos[row]         = p;
        pos[row + NROWS] = p;
    }
    const int gt = blockIdx.x * 256 + threadIdx.x;
    if (gt < N2) rowsum[gt] = 0.f;
    if (gt == 0) out[0] = 0.f;
}

// ---------------------------------------------------------------------------
// Kernel 2: upper-triangle tiled Zp8·Zp8^T (fp8 MFMA), fused exp2 + sums.
// LDS-free packed-fragment GEMM, depth-2 register pipeline (R12), now fp8:
//  - loads are dwordx2 (8B/lane) -> TA line traffic halved vs bf16
//  - frag buffers 48 VGPR (3 bufs x 8 frags x 2) + acc 64 -> fits 128
//    => __launch_bounds__(256,4): 4 waves/SIMD (R12 was capped at 3)
// No K-loop barriers; XCD-locality mapping (R8); no device-scope fences
// (R5); DPP row-sums (R9). fp8 C/D layout == bf16's (shape-determined,
// guide-verified), so the epilogue/diag-mask logic is unchanged.
// ---------------------------------------------------------------------------
__global__ __launch_bounds__(256, 4) void simgemm_kernel(
    const unsigned char* __restrict__ Zp8, float* __restrict__ rowsum)
{
    // ---- XCD-local block -> (bi,bj) mapping (bijection onto upper tri) ----
    const int b = blockIdx.x;
    const int k = b & 7;        // XCD under round-robin dispatch heuristic
    const int m = b >> 3;       // 0..1031 local rank within XCD
    int bi, bj;
    if (m < 136) {
        // diagonal group-pair k: 16x16 upper triangle, cum(t) = t*(33-t)/2
        int ti = (int)((33.0f - sqrtf(1089.0f - 8.0f * (float)m)) * 0.5f);
        if (m < ti * (33 - ti) / 2) ti--;
        else if (m >= (ti + 1) * (32 - ti) / 2) ti++;
        const int tj = ti + (m - ti * (33 - ti) / 2);
        bi = k * 16 + ti;
        bj = k * 16 + tj;
    } else {
        const int m2 = m - 136;          // 0..895
        const int hh = m2 >> 7;          // 0..6  (which of my 7 halves)
        const int r  = m2 & 127;         // 0..127 within half (8x16 tiles)
        const int h  = hh * 8 + k;       // 0..55 global half index
        const int q  = h >> 1;           // 0..27 off-diag group pair
        const int sub = h & 1;
        // pair q -> (gi,gj), gi<gj, cum(gi) = gi*(15-gi)/2
        int gi = 0;
        #pragma unroll
        for (int t = 6; t > 0; --t)
            if (q >= t * (15 - t) / 2) { gi = t; break; }
        const int gj = gi + 1 + (q - gi * (15 - gi) / 2);
        bi = gi * 16 + sub * 8 + (r >> 4);
        bj = gj * 16 + (r & 15);
    }
    const bool diag = (bi == bj);

    __shared__ float rs[BM];
    __shared__ float cs[BM];

    const int tid  = threadIdx.x;
    const int wave = tid >> 6;
    const int lane = tid & 63;
    const int wm   = wave & 1;            // wave row (0..1)
    const int wn   = wave >> 1;           // wave col (0..1)
    const int g    = lane >> 4;           // quad  (0..3)
    const int m15  = lane & 15;

    if (tid < BM) { rs[tid] = 0.f; cs[tid] = 0.f; }
    __syncthreads();   // rs/cs zeroed before any wave's epilogue atomics

    // fragment base pointers (packed fp8 layout, byte addressed):
    // frag (f, s) at base + f*4096 + s*512, lane offset lane*8.
    const unsigned char* pA = Zp8 + (size_t)(bi * 8 + wm * 4) * 4096 + lane * 8;
    const unsigned char* pB = Zp8 + (size_t)(bj * 8 + wn * 4) * 4096 + lane * 8;

    floatx4 acc[4][4] = {};
    long af[3][4], bf[3][4];   // depth-2: 3 buffers, 2 VGPR per frag

    #pragma unroll
    for (int f = 0; f < 4; ++f) {
        af[0][f] = *(const long*)(pA + f * 4096);
        bf[0][f] = *(const long*)(pB + f * 4096);
    }
    #pragma unroll
    for (int f = 0; f < 4; ++f) {
        af[1][f] = *(const long*)(pA + f * 4096 + 512);
        bf[1][f] = *(const long*)(pB + f * 4096 + 512);
    }

    #pragma unroll
    for (int s = 0; s < HDIM / 32; ++s) {   // 8 k-steps, no barriers
        const int cur = s % 3;
        if (s + 2 < HDIM / 32) {
            const int nxt = (s + 2) % 3;
            #pragma unroll
            for (int f = 0; f < 4; ++f) {
                af[nxt][f] = *(const long*)(pA + f * 4096 + (s + 2) * 512);
                bf[nxt][f] = *(const long*)(pB + f * 4096 + (s + 2) * 512);
            }
        }
        #pragma unroll
        for (int fm = 0; fm < 4; ++fm)
            #pragma unroll
            for (int fn = 0; fn < 4; ++fn)
                acc[fm][fn] = __builtin_amdgcn_mfma_f32_16x16x32_fp8_fp8(
                    af[cur][fm], bf[cur][fn], acc[fm][fn], 0, 0, 0);
    }

    // ---- epilogue: e = exp2(acc*C) == exp(sim/tau); reduce rows & cols ----
    float rp[4][4] = {{0.f}};  // [fm][reg] partial row sums
    float cp[4]    = {0.f};    // [fn]      partial col sums

    if (!diag) {
        #pragma unroll
        for (int fm = 0; fm < 4; ++fm)
            #pragma unroll
            for (int fn = 0; fn < 4; ++fn) {
                const floatx4 a = acc[fm][fn];
                #pragma unroll
                for (int q = 0; q < 4; ++q) {
                    const float e = __builtin_amdgcn_exp2f(a[q] * ACC2EXP2);
                    rp[fm][q] += e;
                    cp[fn]    += e;
                }
            }
    } else {
        #pragma unroll
        for (int fm = 0; fm < 4; ++fm)
            #pragma unroll
            for (int fn = 0; fn < 4; ++fn) {
                const floatx4 a = acc[fm][fn];
                const int cl = wn * 64 + fn * 16 + m15;
                #pragma unroll
                for (int q = 0; q < 4; ++q) {
                    const int rl = wm * 64 + fm * 16 + g * 4 + q;
                    float e = __builtin_amdgcn_exp2f(a[q] * ACC2EXP2);
                    if (cl <= rl) e = 0.f;   // strictly-upper only
                    rp[fm][q] += e;
                    cp[fn]    += e;
                }
            }
    }

    // row sums: 16-lane DPP reduction (VALU pipe); total lands in m15==0
    #pragma unroll
    for (int fm = 0; fm < 4; ++fm)
        #pragma unroll
        for (int q = 0; q < 4; ++q) {
            float v = rp[fm][q];
            DPP_ROW_SUM16(v);
            rp[fm][q] = v;
        }
    if (m15 == 0) {
        #pragma unroll
        for (int fm = 0; fm < 4; ++fm)
            #pragma unroll
            for (int q = 0; q < 4; ++q)
                atomicAdd(&rs[wm * 64 + fm * 16 + g * 4 + q], rp[fm][q]);
    }

    // col sums: reduce across quads (xor 16/32 crosses DPP rows -> keep shfl)
    #pragma unroll
    for (int mask = 16; mask < 64; mask <<= 1)
        #pragma unroll
        for (int fn = 0; fn < 4; ++fn)
            cp[fn] += __shfl_xor(cp[fn], mask);
    if (g == 0) {
        #pragma unroll
        for (int fn = 0; fn < 4; ++fn)
            atomicAdd(&cs[wn * 64 + fn * 16 + m15], cp[fn]);
    }

    __syncthreads();
    if (tid < BM) {
        atomicAdd(&rowsum[(size_t)bi * BM + tid], rs[tid]);
        atomicAdd(&rowsum[(size_t)bj * BM + tid], cs[tid]);
    }
}

// ---------------------------------------------------------------------------
// Kernel 3: loss = mean( log(rowsum_i) - 2*pos_i ), 16 blocks + atomic.
// out[0] zeroed by normalize_kernel (stream-ordered).
// ---------------------------------------------------------------------------
__global__ __launch_bounds__(1024) void finalize_kernel(
    const float* __restrict__ rowsum, const float* __restrict__ pos,
    float* __restrict__ out)
{
    const int i = threadIdx.x + blockIdx.x * 1024;
    float s = logf(rowsum[i]) - 2.0f * pos[i];
    #pragma unroll
    for (int off = 32; off; off >>= 1) s += __shfl_down(s, off);
    __shared__ float sh[16];
    const int lt = threadIdx.x;
    if ((lt & 63) == 0) sh[lt >> 6] = s;
    __syncthreads();
    if (lt == 0) {
        float tot = 0.f;
        #pragma unroll
        for (int w = 0; w < 16; ++w) tot += sh[w];
        atomicAdd(out, tot / (float)N2);
    }
}

// ---------------------------------------------------------------------------
extern "C" void kernel_launch(void* const* d_in, const int* in_sizes, int n_in,
                              void* d_out, int out_size, void* d_ws, size_t ws_size,
                              hipStream_t stream)
{
    const float* x = (const float*)d_in[0];
    const float* y = (const float*)d_in[1];

    // workspace: Zp8 fp8 packed [16384*256] (4 MB) | rowsum f32 | pos f32
    unsigned char* Zp8 = (unsigned char*)d_ws;
    float* rowsum = (float*)((char*)d_ws + (size_t)N2 * HDIM);
    float* pos    = rowsum + N2;

    normalize_kernel<<<NROWS / 4, 256, 0, stream>>>(x, y, Zp8, pos, rowsum, (float*)d_out);
    simgemm_kernel<<<NBLK, 256, 0, stream>>>(Zp8, rowsum);
    finalize_kernel<<<N2 / 1024, 1024, 0, stream>>>(rowsum, pos, (float*)d_out);
}